// Round 17
// baseline (36.304 us; speedup 1.0000x reference)
//
#include <hip/hip_runtime.h>

// ---------------------------------------------------------------------------
// INSTRUMENTATION ROUND: R13 structure, k_gemm launched TWICE (idempotent
// pure-store kernel) to measure the marginal cost of one gemm dispatch:
//   dur(R17) - dur(R13=29.0) = gemm_time + per-dispatch overhead.
// This disambiguates "gemm is really ~24us" vs "~20us lives outside kernels".
// ---------------------------------------------------------------------------

using s16x8 = __attribute__((ext_vector_type(8))) short;   // 8 bf16
using f32x4 = __attribute__((ext_vector_type(4))) float;

__device__ inline short f2bf(float f) {
    unsigned u = __builtin_bit_cast(unsigned, f);
    u += 0x7fffu + ((u >> 16) & 1u);          // round-to-nearest-even
    return (short)(u >> 16);
}

// grid 512: blk<256 -> build W rows [blk*4, blk*4+4); blk>=256 -> X->bf16
__global__ __launch_bounds__(256) void k_prep(
    const float* __restrict__ x, const float* __restrict__ u1,
    const float* __restrict__ u2, const float* __restrict__ u3,
    const float* __restrict__ b2, const float* __restrict__ b1c,
    short* __restrict__ Wb, short* __restrict__ Xb) {
    const int blk = blockIdx.x;
    const int tid = threadIdx.x;

    if (blk >= 256) {                          // X f32 -> bf16
        const int base = (blk - 256) * 4096 + tid * 16;
#pragma unroll
        for (int h = 0; h < 2; ++h) {
            float4 f0 = *(const float4*)&x[base + h * 8];
            float4 f1 = *(const float4*)&x[base + h * 8 + 4];
            s16x8 v;
            v[0] = f2bf(f0.x); v[1] = f2bf(f0.y);
            v[2] = f2bf(f0.z); v[3] = f2bf(f0.w);
            v[4] = f2bf(f1.x); v[5] = f2bf(f1.y);
            v[6] = f2bf(f1.z); v[7] = f2bf(f1.w);
            *(s16x8*)&Xb[base + h * 8] = v;
        }
        return;
    }

    __shared__ float b1s[256];
    __shared__ float u1s[128];                 // u1 d-slice [a][e]
    __shared__ float u2s[64 * 17];             // [br][17] padded
    __shared__ float u3s[4096];                // full u3, linear
    __shared__ float C2t[256 * 17];            // [ep][17] padded
    __shared__ float T1s[2048];                // [a][ps]
    __shared__ float T2s[64 * 17];             // [ab][17] padded
    const int d = blk >> 5;
    const int r = (blk >> 2) & 7;
    const int t0 = (blk & 3) * 4;

    // ---- stage all small tensors (coalesced) ----
    b1s[tid] = b1c[tid];
    {
        float4* dst = (float4*)u3s;
        const float4* src = (const float4*)u3;
#pragma unroll
        for (int q = 0; q < 4; ++q) dst[tid + 256 * q] = src[tid + 256 * q];
    }
    if (tid < 64) {                            // u2 row tid -> padded
        const float4* src = (const float4*)&u2[tid * 16];
#pragma unroll
        for (int q = 0; q < 4; ++q) {
            float4 v = src[q];
            u2s[tid * 17 + q * 4 + 0] = v.x;
            u2s[tid * 17 + q * 4 + 1] = v.y;
            u2s[tid * 17 + q * 4 + 2] = v.z;
            u2s[tid * 17 + q * 4 + 3] = v.w;
        }
    }
    if (tid < 8) {                             // u1 slice: a = tid
#pragma unroll
        for (int e = 0; e < 16; ++e)
            u1s[tid * 16 + e] = u1[(tid * 8 + d) * 16 + e];
    }
    float b2r[16];                             // b2 row (e,p) = tid
    {
        const float4* src = (const float4*)&b2[tid * 16];
#pragma unroll
        for (int q = 0; q < 4; ++q) {
            float4 v = src[q];
            b2r[q * 4 + 0] = v.x; b2r[q * 4 + 1] = v.y;
            b2r[q * 4 + 2] = v.z; b2r[q * 4 + 3] = v.w;
        }
    }
    __syncthreads();

    // ---- C2: thread owns (e,p)=tid; b1s reads are wave-broadcast ----
    {
        float accs[16] = {};
#pragma unroll
        for (int q = 0; q < 16; ++q) {
            const float bq = b2r[q];
#pragma unroll
            for (int s = 0; s < 16; ++s) accs[s] += bq * b1s[q * 16 + s];
        }
#pragma unroll
        for (int s = 0; s < 16; ++s) C2t[tid * 17 + s] = accs[s];
    }
    __syncthreads();

    // ---- T1[a][ps]: thread owns ps=tid; C2t reads <=2-way ----
    {
        const int p = tid >> 4, s = tid & 15;
#pragma unroll
        for (int a = 0; a < 8; ++a) {
            float acc = 0.f;
#pragma unroll
            for (int e = 0; e < 16; ++e)
                acc += u1s[a * 16 + e] * C2t[(e * 16 + p) * 17 + s];
            T1s[a * 256 + tid] = acc;
        }
    }
    __syncthreads();

    // ---- T2[ab][s] (r fixed): T1s reads broadcast, u2s <=2-way ----
#pragma unroll
    for (int j = 0; j < 4; ++j) {
        int idx = tid + 256 * j;
        int ab = idx >> 4, s = idx & 15;
        int a = ab >> 3, b = ab & 7;
        float acc = 0.f;
#pragma unroll
        for (int p = 0; p < 16; ++p)
            acc += T1s[a * 256 + p * 16 + s] * u2s[(b * 8 + r) * 17 + p];
        T2s[ab * 17 + s] = acc;
    }
    __syncthreads();

    // ---- W rows o = blk*4 + j: u3s reads wave-broadcast, T2s 2-way ----
    {
        const int j = tid >> 6;
        const int t = t0 + j;
        const int col0 = (tid & 63) * 16;
        const int ab = col0 >> 4;
        const float* t2p = &T2s[ab * 17];
        short* wrow = &Wb[(blk * 4 + j) * 1024 + col0];
        s16x8 v0, v1;
#pragma unroll
        for (int c = 0; c < 16; ++c) {
            const float* u3p = &u3s[c * 256 + t * 16];
            float acc = 0.f;
#pragma unroll
            for (int s = 0; s < 16; ++s) acc += t2p[s] * u3p[s];
            short bf = f2bf(acc);
            if (c < 8) v0[c] = bf; else v1[c - 8] = bf;
        }
        *(s16x8*)(wrow) = v0;
        *(s16x8*)(wrow + 8) = v1;
    }
}

// ---------------------------------------------------------------------------
// Split-K MFMA GEMM (R12/R13-proven). Grid (16 o, 16 z, 4 kz); 256 thr.
// ---------------------------------------------------------------------------
#define LDK 136

__global__ __launch_bounds__(256) void k_gemm(
    const short* __restrict__ Xb, const short* __restrict__ Wb,
    float* __restrict__ PH) {
    __shared__ short As[64][LDK];              // 17408 B
    __shared__ short Bs[64][LDK];              // 17408 B
    const int tid = threadIdx.x;
    const int lane = tid & 63;
    const int w = tid >> 6, wr = w >> 1, wc = w & 1;
    const int o0 = blockIdx.x * 64, z0 = blockIdx.y * 64, kz = blockIdx.z;
    const int srow = tid >> 2;                 // 0..63, 4 thr/row
    const int sc = (tid & 3) * 16;             // halves at +0,+64

    const short* xp = &Xb[(z0 + srow) * 1024 + kz * 256 + sc];
    const short* wp = &Wb[(o0 + srow) * 1024 + kz * 256 + sc];

    f32x4 acc[2][2] = {};
    s16x8 ax[4], bx[4];                        // [h*2+q]

#pragma unroll
    for (int h = 0; h < 2; ++h)
#pragma unroll
        for (int q = 0; q < 2; ++q) {
            ax[h * 2 + q] = *(const s16x8*)(xp + h * 64 + q * 8);
            bx[h * 2 + q] = *(const s16x8*)(wp + h * 64 + q * 8);
        }

#pragma unroll
    for (int it = 0; it < 2; ++it) {
#pragma unroll
        for (int h = 0; h < 2; ++h)
#pragma unroll
            for (int q = 0; q < 2; ++q) {
                *(s16x8*)&As[srow][sc + h * 64 + q * 8] = ax[h * 2 + q];
                *(s16x8*)&Bs[srow][sc + h * 64 + q * 8] = bx[h * 2 + q];
            }
        __syncthreads();
        if (it == 0) {                         // prefetch second half-slice
#pragma unroll
            for (int h = 0; h < 2; ++h)
#pragma unroll
                for (int q = 0; q < 2; ++q) {
                    ax[h * 2 + q] = *(const s16x8*)(xp + 128 + h * 64 + q * 8);
                    bx[h * 2 + q] = *(const s16x8*)(wp + 128 + h * 64 + q * 8);
                }
        }
#pragma unroll
        for (int ks = 0; ks < 4; ++ks) {
            const int kb = ks * 32 + (lane >> 4) * 8;
            s16x8 a0 = *(const s16x8*)&As[wr * 32 + (lane & 15)][kb];
            s16x8 a1 = *(const s16x8*)&As[wr * 32 + 16 + (lane & 15)][kb];
            s16x8 b0 = *(const s16x8*)&Bs[wc * 32 + (lane & 15)][kb];
            s16x8 b1 = *(const s16x8*)&Bs[wc * 32 + 16 + (lane & 15)][kb];
            acc[0][0] = __builtin_amdgcn_mfma_f32_16x16x32_bf16(a0, b0, acc[0][0], 0, 0, 0);
            acc[0][1] = __builtin_amdgcn_mfma_f32_16x16x32_bf16(a0, b1, acc[0][1], 0, 0, 0);
            acc[1][0] = __builtin_amdgcn_mfma_f32_16x16x32_bf16(a1, b0, acc[1][0], 0, 0, 0);
            acc[1][1] = __builtin_amdgcn_mfma_f32_16x16x32_bf16(a1, b1, acc[1][1], 0, 0, 0);
        }
        __syncthreads();
    }

    // partial C store: D layout col=lane&15, row=(lane>>4)*4+j
    float* ph = &PH[(unsigned)kz * 1048576u];
#pragma unroll
    for (int m = 0; m < 2; ++m)
#pragma unroll
        for (int n = 0; n < 2; ++n) {
            const int row = z0 + wr * 32 + m * 16 + (lane >> 4) * 4;
            const int col = o0 + wc * 32 + n * 16 + (lane & 15);
#pragma unroll
            for (int j = 0; j < 4; ++j)
                ph[(row + j) * 1024 + col] = acc[m][n][j];
        }
}

// ---------------------------------------------------------------------------
// k_out: H = relu(sum of 4 PH slices + bias1); out = H @ fc2_w^T + fc2_b.
// ---------------------------------------------------------------------------
__global__ __launch_bounds__(256) void k_out(
    const float* __restrict__ PH, const float* __restrict__ bias1,
    const float* __restrict__ W2, const float* __restrict__ fc2b,
    float* __restrict__ out) {
    __shared__ float W2s[10][1024];            // 40 KB
    const int tid = threadIdx.x;
#pragma unroll
    for (int i = 0; i < 10; ++i) {             // stage all of fc2_w
        const int idx = tid + 256 * i;         // 2560 float4
        ((float4*)W2s)[idx] = ((const float4*)W2)[idx];
    }
    __syncthreads();

    const int wid = tid >> 6, lane = tid & 63;
    const int z = blockIdx.x * 4 + wid;
    float part[10];
#pragma unroll
    for (int j = 0; j < 10; ++j) part[j] = 0.f;
#pragma unroll
    for (int i = 0; i < 16; ++i) {
        const int col = lane + 64 * i;
        float h = PH[z * 1024 + col] + PH[1048576 + z * 1024 + col]
                + PH[2097152 + z * 1024 + col] + PH[3145728 + z * 1024 + col];
        h = fmaxf(h + bias1[col], 0.f);
#pragma unroll
        for (int j = 0; j < 10; ++j) part[j] += h * W2s[j][col];
    }
#pragma unroll
    for (int j = 0; j < 10; ++j) {
#pragma unroll
        for (int off = 32; off > 0; off >>= 1) part[j] += __shfl_xor(part[j], off);
    }
    if (lane == 0) {
#pragma unroll
        for (int j = 0; j < 10; ++j) out[z * 10 + j] = part[j] + fc2b[j];
    }
}

extern "C" void kernel_launch(void* const* d_in, const int* in_sizes, int n_in,
                              void* d_out, int out_size, void* d_ws, size_t ws_size,
                              hipStream_t stream) {
    const float* x     = (const float*)d_in[0];
    const float* u1    = (const float*)d_in[1];
    const float* u2    = (const float*)d_in[2];
    const float* u3    = (const float*)d_in[3];
    const float* b2    = (const float*)d_in[4];
    const float* b1c   = (const float*)d_in[5];
    const float* bias1 = (const float*)d_in[6];
    const float* fc2w  = (const float*)d_in[7];
    const float* fc2b  = (const float*)d_in[8];
    float* out = (float*)d_out;

    short* Wb = (short*)d_ws;                                  // 2 MB bf16
    short* Xb = (short*)((char*)d_ws + 2u * 1024u * 1024u);    // 2 MB bf16
    float* PH = (float*)((char*)d_ws + 4u * 1024u * 1024u);    // 16 MB f32

    k_prep<<<512, 256, 0, stream>>>(x, u1, u2, u3, b2, b1c, Wb, Xb);
    // INSTRUMENTATION: k_gemm twice (idempotent). dur - 29.0 = gemm + launch.
    k_gemm<<<dim3(16, 16, 4), 256, 0, stream>>>(Xb, Wb, PH);
    k_gemm<<<dim3(16, 16, 4), 256, 0, stream>>>(Xb, Wb, PH);
    k_out<<<256, 256, 0, stream>>>(PH, bias1, fc2w, fc2b, out);
}

// Round 18
// 29.049 us; speedup vs baseline: 1.2497x; 1.2497x over previous
//
#include <hip/hip_runtime.h>

// ---------------------------------------------------------------------------
// tNet: einsum chain is linear in x. R13 structure (best: 29.0us) + trims:
//   - k_out: float4 PH loads (was 4096 scalar loads/wave -> 1024 float4)
//   - k_gemm: peeled final iteration (dead trailing barrier removed)
// Measured decomposition (R17 instrumentation): dur = ~20us fixed replay
// overhead + prep ~1.5 + gemm ~4.5-7 + out ~2.5. Kernel-side headroom ~2us.
//   t5[z,d,r,t] = sum_{a,b,c,e,p,q,s} x[z,a,b,c] u1[a,d,e] b2[e,p,q]
//                                     u2[b,r,p] b1c[q,s] u3[c,t,s]
//   o = d*128+r*16+t ; i = a*128+b*16+c
// ---------------------------------------------------------------------------

using s16x8 = __attribute__((ext_vector_type(8))) short;   // 8 bf16
using f32x4 = __attribute__((ext_vector_type(4))) float;

__device__ inline short f2bf(float f) {
    unsigned u = __builtin_bit_cast(unsigned, f);
    u += 0x7fffu + ((u >> 16) & 1u);          // round-to-nearest-even
    return (short)(u >> 16);
}

// grid 512: blk<256 -> build W rows [blk*4, blk*4+4); blk>=256 -> X->bf16
__global__ __launch_bounds__(256) void k_prep(
    const float* __restrict__ x, const float* __restrict__ u1,
    const float* __restrict__ u2, const float* __restrict__ u3,
    const float* __restrict__ b2, const float* __restrict__ b1c,
    short* __restrict__ Wb, short* __restrict__ Xb) {
    const int blk = blockIdx.x;
    const int tid = threadIdx.x;

    if (blk >= 256) {                          // X f32 -> bf16
        const int base = (blk - 256) * 4096 + tid * 16;
#pragma unroll
        for (int h = 0; h < 2; ++h) {
            float4 f0 = *(const float4*)&x[base + h * 8];
            float4 f1 = *(const float4*)&x[base + h * 8 + 4];
            s16x8 v;
            v[0] = f2bf(f0.x); v[1] = f2bf(f0.y);
            v[2] = f2bf(f0.z); v[3] = f2bf(f0.w);
            v[4] = f2bf(f1.x); v[5] = f2bf(f1.y);
            v[6] = f2bf(f1.z); v[7] = f2bf(f1.w);
            *(s16x8*)&Xb[base + h * 8] = v;
        }
        return;
    }

    __shared__ float b1s[256];
    __shared__ float u1s[128];                 // u1 d-slice [a][e]
    __shared__ float u2s[64 * 17];             // [br][17] padded
    __shared__ float u3s[4096];                // full u3, linear
    __shared__ float C2t[256 * 17];            // [ep][17] padded
    __shared__ float T1s[2048];                // [a][ps]
    __shared__ float T2s[64 * 17];             // [ab][17] padded
    const int d = blk >> 5;
    const int r = (blk >> 2) & 7;
    const int t0 = (blk & 3) * 4;

    // ---- stage all small tensors (coalesced) ----
    b1s[tid] = b1c[tid];
    {
        float4* dst = (float4*)u3s;
        const float4* src = (const float4*)u3;
#pragma unroll
        for (int q = 0; q < 4; ++q) dst[tid + 256 * q] = src[tid + 256 * q];
    }
    if (tid < 64) {                            // u2 row tid -> padded
        const float4* src = (const float4*)&u2[tid * 16];
#pragma unroll
        for (int q = 0; q < 4; ++q) {
            float4 v = src[q];
            u2s[tid * 17 + q * 4 + 0] = v.x;
            u2s[tid * 17 + q * 4 + 1] = v.y;
            u2s[tid * 17 + q * 4 + 2] = v.z;
            u2s[tid * 17 + q * 4 + 3] = v.w;
        }
    }
    if (tid < 8) {                             // u1 slice: a = tid
#pragma unroll
        for (int e = 0; e < 16; ++e)
            u1s[tid * 16 + e] = u1[(tid * 8 + d) * 16 + e];
    }
    float b2r[16];                             // b2 row (e,p) = tid
    {
        const float4* src = (const float4*)&b2[tid * 16];
#pragma unroll
        for (int q = 0; q < 4; ++q) {
            float4 v = src[q];
            b2r[q * 4 + 0] = v.x; b2r[q * 4 + 1] = v.y;
            b2r[q * 4 + 2] = v.z; b2r[q * 4 + 3] = v.w;
        }
    }
    __syncthreads();

    // ---- C2: thread owns (e,p)=tid; b1s reads are wave-broadcast ----
    {
        float accs[16] = {};
#pragma unroll
        for (int q = 0; q < 16; ++q) {
            const float bq = b2r[q];
#pragma unroll
            for (int s = 0; s < 16; ++s) accs[s] += bq * b1s[q * 16 + s];
        }
#pragma unroll
        for (int s = 0; s < 16; ++s) C2t[tid * 17 + s] = accs[s];
    }
    __syncthreads();

    // ---- T1[a][ps]: thread owns ps=tid; C2t reads <=2-way ----
    {
        const int p = tid >> 4, s = tid & 15;
#pragma unroll
        for (int a = 0; a < 8; ++a) {
            float acc = 0.f;
#pragma unroll
            for (int e = 0; e < 16; ++e)
                acc += u1s[a * 16 + e] * C2t[(e * 16 + p) * 17 + s];
            T1s[a * 256 + tid] = acc;
        }
    }
    __syncthreads();

    // ---- T2[ab][s] (r fixed): T1s reads broadcast, u2s <=2-way ----
#pragma unroll
    for (int j = 0; j < 4; ++j) {
        int idx = tid + 256 * j;
        int ab = idx >> 4, s = idx & 15;
        int a = ab >> 3, b = ab & 7;
        float acc = 0.f;
#pragma unroll
        for (int p = 0; p < 16; ++p)
            acc += T1s[a * 256 + p * 16 + s] * u2s[(b * 8 + r) * 17 + p];
        T2s[ab * 17 + s] = acc;
    }
    __syncthreads();

    // ---- W rows o = blk*4 + j: u3s reads wave-broadcast, T2s 2-way ----
    {
        const int j = tid >> 6;
        const int t = t0 + j;
        const int col0 = (tid & 63) * 16;
        const int ab = col0 >> 4;
        const float* t2p = &T2s[ab * 17];
        short* wrow = &Wb[(blk * 4 + j) * 1024 + col0];
        s16x8 v0, v1;
#pragma unroll
        for (int c = 0; c < 16; ++c) {
            const float* u3p = &u3s[c * 256 + t * 16];
            float acc = 0.f;
#pragma unroll
            for (int s = 0; s < 16; ++s) acc += t2p[s] * u3p[s];
            short bf = f2bf(acc);
            if (c < 8) v0[c] = bf; else v1[c - 8] = bf;
        }
        *(s16x8*)(wrow) = v0;
        *(s16x8*)(wrow + 8) = v1;
    }
}

// ---------------------------------------------------------------------------
// Split-K MFMA GEMM (R12/R13-proven). Grid (16 o, 16 z, 4 kz); 256 thr.
// Final iteration peeled (no dead trailing barrier).
// ---------------------------------------------------------------------------
#define LDK 136

__global__ __launch_bounds__(256) void k_gemm(
    const short* __restrict__ Xb, const short* __restrict__ Wb,
    float* __restrict__ PH) {
    __shared__ short As[64][LDK];              // 17408 B
    __shared__ short Bs[64][LDK];              // 17408 B
    const int tid = threadIdx.x;
    const int lane = tid & 63;
    const int w = tid >> 6, wr = w >> 1, wc = w & 1;
    const int o0 = blockIdx.x * 64, z0 = blockIdx.y * 64, kz = blockIdx.z;
    const int srow = tid >> 2;                 // 0..63, 4 thr/row
    const int sc = (tid & 3) * 16;             // halves at +0,+64

    const short* xp = &Xb[(z0 + srow) * 1024 + kz * 256 + sc];
    const short* wp = &Wb[(o0 + srow) * 1024 + kz * 256 + sc];

    f32x4 acc[2][2] = {};
    s16x8 ax[4], bx[4];                        // [h*2+q]

#pragma unroll
    for (int h = 0; h < 2; ++h)
#pragma unroll
        for (int q = 0; q < 2; ++q) {
            ax[h * 2 + q] = *(const s16x8*)(xp + h * 64 + q * 8);
            bx[h * 2 + q] = *(const s16x8*)(wp + h * 64 + q * 8);
        }

#define MFMA_PHASE                                                            \
    _Pragma("unroll")                                                         \
    for (int ks = 0; ks < 4; ++ks) {                                          \
        const int kb = ks * 32 + (lane >> 4) * 8;                             \
        s16x8 a0 = *(const s16x8*)&As[wr * 32 + (lane & 15)][kb];             \
        s16x8 a1 = *(const s16x8*)&As[wr * 32 + 16 + (lane & 15)][kb];        \
        s16x8 b0 = *(const s16x8*)&Bs[wc * 32 + (lane & 15)][kb];             \
        s16x8 b1 = *(const s16x8*)&Bs[wc * 32 + 16 + (lane & 15)][kb];        \
        acc[0][0] = __builtin_amdgcn_mfma_f32_16x16x32_bf16(a0, b0, acc[0][0], 0, 0, 0); \
        acc[0][1] = __builtin_amdgcn_mfma_f32_16x16x32_bf16(a0, b1, acc[0][1], 0, 0, 0); \
        acc[1][0] = __builtin_amdgcn_mfma_f32_16x16x32_bf16(a1, b0, acc[1][0], 0, 0, 0); \
        acc[1][1] = __builtin_amdgcn_mfma_f32_16x16x32_bf16(a1, b1, acc[1][1], 0, 0, 0); \
    }

    // iteration 0: stage, prefetch, compute, barrier
#pragma unroll
    for (int h = 0; h < 2; ++h)
#pragma unroll
        for (int q = 0; q < 2; ++q) {
            *(s16x8*)&As[srow][sc + h * 64 + q * 8] = ax[h * 2 + q];
            *(s16x8*)&Bs[srow][sc + h * 64 + q * 8] = bx[h * 2 + q];
        }
    __syncthreads();
#pragma unroll
    for (int h = 0; h < 2; ++h)
#pragma unroll
        for (int q = 0; q < 2; ++q) {
            ax[h * 2 + q] = *(const s16x8*)(xp + 128 + h * 64 + q * 8);
            bx[h * 2 + q] = *(const s16x8*)(wp + 128 + h * 64 + q * 8);
        }
    MFMA_PHASE
    __syncthreads();

    // iteration 1 (peeled): stage, compute, NO trailing barrier
#pragma unroll
    for (int h = 0; h < 2; ++h)
#pragma unroll
        for (int q = 0; q < 2; ++q) {
            *(s16x8*)&As[srow][sc + h * 64 + q * 8] = ax[h * 2 + q];
            *(s16x8*)&Bs[srow][sc + h * 64 + q * 8] = bx[h * 2 + q];
        }
    __syncthreads();
    MFMA_PHASE
#undef MFMA_PHASE

    // partial C store: D layout col=lane&15, row=(lane>>4)*4+j
    float* ph = &PH[(unsigned)kz * 1048576u];
#pragma unroll
    for (int m = 0; m < 2; ++m)
#pragma unroll
        for (int n = 0; n < 2; ++n) {
            const int row = z0 + wr * 32 + m * 16 + (lane >> 4) * 4;
            const int col = o0 + wc * 32 + n * 16 + (lane & 15);
#pragma unroll
            for (int j = 0; j < 4; ++j)
                ph[(row + j) * 1024 + col] = acc[m][n][j];
        }
}

// ---------------------------------------------------------------------------
// k_out: H = relu(sum of 4 PH slices + bias1); out = H @ fc2_w^T + fc2_b.
// 256 blocks x 256 thr; one wave per z-row. float4 PH/bias loads (G13).
// ---------------------------------------------------------------------------
__global__ __launch_bounds__(256) void k_out(
    const float* __restrict__ PH, const float* __restrict__ bias1,
    const float* __restrict__ W2, const float* __restrict__ fc2b,
    float* __restrict__ out) {
    __shared__ float W2s[10][1024];            // 40 KB
    const int tid = threadIdx.x;
#pragma unroll
    for (int i = 0; i < 10; ++i) {             // stage all of fc2_w
        const int idx = tid + 256 * i;         // 2560 float4
        ((float4*)W2s)[idx] = ((const float4*)W2)[idx];
    }
    __syncthreads();

    const int wid = tid >> 6, lane = tid & 63;
    const int z = blockIdx.x * 4 + wid;
    const float4* p0 = (const float4*)&PH[z * 1024];
    const float4* p1 = (const float4*)&PH[1048576 + z * 1024];
    const float4* p2 = (const float4*)&PH[2097152 + z * 1024];
    const float4* p3 = (const float4*)&PH[3145728 + z * 1024];
    const float4* bv4 = (const float4*)bias1;
    float part[10];
#pragma unroll
    for (int j = 0; j < 10; ++j) part[j] = 0.f;
#pragma unroll
    for (int i = 0; i < 4; ++i) {              // 4 float4 per lane
        const int c4 = lane + 64 * i;          // float4 index (col = c4*4)
        float4 a = p0[c4], b = p1[c4], c = p2[c4], dd = p3[c4];
        float4 bb = bv4[c4];
        float h0 = fmaxf(a.x + b.x + c.x + dd.x + bb.x, 0.f);
        float h1 = fmaxf(a.y + b.y + c.y + dd.y + bb.y, 0.f);
        float h2 = fmaxf(a.z + b.z + c.z + dd.z + bb.z, 0.f);
        float h3 = fmaxf(a.w + b.w + c.w + dd.w + bb.w, 0.f);
        const int col = c4 * 4;
#pragma unroll
        for (int j = 0; j < 10; ++j)
            part[j] += h0 * W2s[j][col] + h1 * W2s[j][col + 1]
                     + h2 * W2s[j][col + 2] + h3 * W2s[j][col + 3];
    }
#pragma unroll
    for (int j = 0; j < 10; ++j) {
#pragma unroll
        for (int off = 32; off > 0; off >>= 1) part[j] += __shfl_xor(part[j], off);
    }
    if (lane == 0) {
#pragma unroll
        for (int j = 0; j < 10; ++j) out[z * 10 + j] = part[j] + fc2b[j];
    }
}

extern "C" void kernel_launch(void* const* d_in, const int* in_sizes, int n_in,
                              void* d_out, int out_size, void* d_ws, size_t ws_size,
                              hipStream_t stream) {
    const float* x     = (const float*)d_in[0];
    const float* u1    = (const float*)d_in[1];
    const float* u2    = (const float*)d_in[2];
    const float* u3    = (const float*)d_in[3];
    const float* b2    = (const float*)d_in[4];
    const float* b1c   = (const float*)d_in[5];
    const float* bias1 = (const float*)d_in[6];
    const float* fc2w  = (const float*)d_in[7];
    const float* fc2b  = (const float*)d_in[8];
    float* out = (float*)d_out;

    short* Wb = (short*)d_ws;                                  // 2 MB bf16
    short* Xb = (short*)((char*)d_ws + 2u * 1024u * 1024u);    // 2 MB bf16
    float* PH = (float*)((char*)d_ws + 4u * 1024u * 1024u);    // 16 MB f32

    k_prep<<<512, 256, 0, stream>>>(x, u1, u2, u3, b2, b1c, Wb, Xb);
    k_gemm<<<dim3(16, 16, 4), 256, 0, stream>>>(Xb, Wb, PH);
    k_out<<<256, 256, 0, stream>>>(PH, bias1, fc2w, fc2b, out);
}